// Round 2
// baseline (203.099 us; speedup 1.0000x reference)
//
#include <hip/hip_runtime.h>

#define N_DATA   128
#define SEG_LEN  131072
#define NPROD    (SEG_LEN - 1)
#define N_MAT    8
#define N_MATP   8
#define N_PROCP  5
#define RGAS     8.314f

#define TPB      256
#define EPT      16                   // elements per lane
#define WCHUNK   (64 * EPT)           // 1024 elements per wave
#define WPR      (SEG_LEN / WCHUNK)   // 128 wave-slots per row
#define NWAVE    (N_DATA * WPR)       // 16384 waves total
#define NBLK     (NWAVE / (TPB / 64)) // 4096 blocks (4 independent waves each)

typedef float nt4 __attribute__((ext_vector_type(4)));  // native vec for nontemporal builtin

// sigma_ss = (base_num*u*Lg + Sigma0*cbd) / (Lg*(u+cbd)),  u = R*Lg + 1e-9
__device__ __forceinline__ float stress_s(float t,
    float alpha1, float L0, float G200, float Sigma0, float A0,
    float inv_tau, float cbd, float base_num, float R) {
  float Lg  = G200 * __expf(alpha1 * __logf(t * (1.0f / 200.0f) + 0.001f)) + L0;
  float u   = R * Lg + 1e-9f;
  float num = base_num * u * Lg + Sigma0 * cbd;
  float den = Lg * (u + cbd);
  float sigma_ss = num * __builtin_amdgcn_rcpf(den);
  return sigma_ss + A0 * __expf(-t * inv_tau);
}

// K0: re-arm the packed {ready|value} words (workspace is re-poisoned between
// iterations; poison bits could fake "ready"). Kernel => graph-capture-safe.
__global__ __launch_bounds__(TPB) void k0_init(unsigned long long* __restrict__ cs) {
  cs[blockIdx.x * TPB + threadIdx.x] = 0ull;
}

// Single-pass scan, WAVE-grained, zero barriers, zero LDS.
// Wave w owns elements [w*1024, w*1024+1024) of the flat array (row = w>>7).
//  1. params: lanes 0..12 compute one sigmoid each, __shfl broadcast
//  2. products + per-lane running sum + 64-lane shuffle scan
//  3. lane 63 publishes wave total (packed {ready<<32|bits}, relaxed
//     agent-scope atomic) -- earliest possible publish, no barrier
//  4. poll <=127 same-row predecessor slots (<=2 per lane; predecessors all
//     have lower blockIdx => in-order dispatch guarantees forward progress,
//     same assumption as rocPRIM's single-pass scan), shfl-reduce to offset
//  5. two.. four aligned nontemporal float4 stores (out[i] = K0 + prefix(i-1))
// No intra-block coupling: each wave proceeds the moment ITS wait resolves.
__global__ __launch_bounds__(TPB) void k_scan(
    const float* __restrict__ x,
    const float* __restrict__ pc, const float* __restrict__ raw,
    const float* __restrict__ lb, const float* __restrict__ ub,
    const float* __restrict__ sc, const int* __restrict__ mat_idx,
    unsigned long long* __restrict__ cs,
    float* __restrict__ out) {
  int tid  = threadIdx.x;
  int lane = tid & 63;
  int w    = blockIdx.x * (TPB >> 6) + (tid >> 6);    // global wave id
  int row  = __builtin_amdgcn_readfirstlane(w >> 7);  // wave-uniform -> SGPR
  int s    = w & (WPR - 1);                           // wave slot within row

  // issue x loads immediately (fly during param compute)
  long rowbase = (long)row * SEG_LEN;
  int  gbl = s * WCHUNK + lane * EPT;                 // row-local offset
  const float* xp = x + rowbase + gbl;
  float4 a0 = *(const float4*)(xp);
  float4 a1 = *(const float4*)(xp + 4);
  float4 a2 = *(const float4*)(xp + 8);
  float4 a3 = *(const float4*)(xp + 12);
  float  xn = (gbl + EPT < SEG_LEN) ? xp[EPT] : 0.0f;

  // param transform: lanes 0..12 compute one sigmoid each; broadcast by shfl
  float pvl = 0.0f;
  if (lane < 13) {
    int idx = (lane < 5) ? (N_MAT * N_MATP + row * N_PROCP + lane)
                         : (mat_idx[row] * N_MATP + (lane - 5));
    float sg = 1.0f / (1.0f + __expf(-raw[idx]));
    pvl = sg * (ub[idx] - lb[idx]) + lb[idx];
  }
  float SigmaC = __shfl(pvl, 0),  K0   = __shfl(pvl, 1), alpha1 = __shfl(pvl, 2);
  float L0     = __shfl(pvl, 3),  G200 = __shfl(pvl, 4);
  float Sigma0 = __shfl(pvl, 5),  BetaD = __shfl(pvl, 6), Ea = __shfl(pvl, 7);
  float Mfda   = __shfl(pvl, 8),  Di   = __shfl(pvl, 9);
  float A0     = __shfl(pvl, 10), B0   = __shfl(pvl, 11), l0 = __shfl(pvl, 12);

  float R = pc[row * 4 + 0], T = pc[row * 4 + 1], P = pc[row * 4 + 2];
  float cbd      = BetaD * Di * __expf(-Ea / (RGAS * T));
  float base_num = SigmaC - Mfda * P;
  float inv_tau  = 1.0f / (B0 * l0 + 1e-9f);
  float x_min = sc[0], x_sc = sc[1] - sc[0];
  float y_min = sc[2], inv_yr = 1.0f / (sc[3] - sc[2]);

  float xr[EPT + 1];
  xr[0]=a0.x; xr[1]=a0.y; xr[2]=a0.z; xr[3]=a0.w;
  xr[4]=a1.x; xr[5]=a1.y; xr[6]=a1.z; xr[7]=a1.w;
  xr[8]=a2.x; xr[9]=a2.y; xr[10]=a2.z; xr[11]=a2.w;
  xr[12]=a3.x; xr[13]=a3.y; xr[14]=a3.z; xr[15]=a3.w;
  xr[16]=xn;

  float pref[EPT];
  float run  = 0.0f;
  float tcur = xr[0] * x_sc + x_min;
#pragma unroll
  for (int k = 0; k < EPT; k++) {
    float tnext = xr[k + 1] * x_sc + x_min;
    float p = 0.0f;
    if (gbl + k < NPROD) {
      float ss = stress_s(tcur, alpha1, L0, G200, Sigma0, A0, inv_tau, cbd, base_num, R);
      p = ss * (tnext - tcur);
    }
    run += p;
    pref[k] = run;   // inclusive within lane
    tcur = tnext;
  }

  // 64-lane inclusive scan of per-lane sums
  float incl = run;
#pragma unroll
  for (int d = 1; d < 64; d <<= 1) {
    float n = __shfl_up(incl, d);
    if (lane >= d) incl += n;
  }

  // publish wave total ASAP: lane 63 holds it after the scan
  if (lane == 63) {
    unsigned long long u = (1ull << 32) |
        (unsigned long long)__float_as_uint(incl);
    __hip_atomic_store(cs + w, u, __ATOMIC_RELAXED, __HIP_MEMORY_SCOPE_AGENT);
  }

  // poll same-row predecessor slots (lane-strided, <=2 words per lane)
  float v = 0.0f;
  for (int c = lane; c < s; c += 64) {
    const unsigned long long* p = cs + ((row << 7) + c);
    unsigned long long u;
    do {
      u = __hip_atomic_load(p, __ATOMIC_RELAXED, __HIP_MEMORY_SCOPE_AGENT);
    } while (!(unsigned)(u >> 32));
    v += __uint_as_float((unsigned)u);
  }
#pragma unroll
  for (int d = 32; d > 0; d >>= 1) v += __shfl_down(v, d);
  float choff = __shfl(v, 0);

  // out[i] = K0 + prefix(i-1): per-lane base uses exclusive scan (incl - run)
  float base = K0 + choff + (incl - run);
  nt4 o0, o1, o2, o3;
  o0.x = (base            - y_min) * inv_yr;
  o0.y = (base + pref[0]  - y_min) * inv_yr;
  o0.z = (base + pref[1]  - y_min) * inv_yr;
  o0.w = (base + pref[2]  - y_min) * inv_yr;
  o1.x = (base + pref[3]  - y_min) * inv_yr;
  o1.y = (base + pref[4]  - y_min) * inv_yr;
  o1.z = (base + pref[5]  - y_min) * inv_yr;
  o1.w = (base + pref[6]  - y_min) * inv_yr;
  o2.x = (base + pref[7]  - y_min) * inv_yr;
  o2.y = (base + pref[8]  - y_min) * inv_yr;
  o2.z = (base + pref[9]  - y_min) * inv_yr;
  o2.w = (base + pref[10] - y_min) * inv_yr;
  o3.x = (base + pref[11] - y_min) * inv_yr;
  o3.y = (base + pref[12] - y_min) * inv_yr;
  o3.z = (base + pref[13] - y_min) * inv_yr;
  o3.w = (base + pref[14] - y_min) * inv_yr;
  nt4* op = (nt4*)(out + rowbase + gbl);
  __builtin_nontemporal_store(o0, op);      // out never re-read: bypass caches,
  __builtin_nontemporal_store(o1, op + 1);  // preserve x's L2/L3 residency
  __builtin_nontemporal_store(o2, op + 2);
  __builtin_nontemporal_store(o3, op + 3);
}

extern "C" void kernel_launch(void* const* d_in, const int* in_sizes, int n_in,
                              void* d_out, int out_size, void* d_ws, size_t ws_size,
                              hipStream_t stream) {
  const float* x_scaled  = (const float*)d_in[0];
  const float* process_c = (const float*)d_in[1];
  const float* raw       = (const float*)d_in[2];
  const float* lb        = (const float*)d_in[3];
  const float* ub        = (const float*)d_in[4];
  const float* sc        = (const float*)d_in[5];
  // d_in[6] = fit_index (unused by the reference computation)
  const int*   mat_idx   = (const int*)d_in[7];
  float* out = (float*)d_out;
  unsigned long long* cs = (unsigned long long*)d_ws;  // 16384 packed {ready|sum}

  k0_init<<<NWAVE / TPB, TPB, 0, stream>>>(cs);
  k_scan<<<NBLK, TPB, 0, stream>>>(
      x_scaled, process_c, raw, lb, ub, sc, mat_idx, cs, out);
}

// Round 4
// 181.015 us; speedup vs baseline: 1.1220x; 1.1220x over previous
//
#include <hip/hip_runtime.h>

#define N_DATA   128
#define SEG_LEN  131072
#define NPROD    (SEG_LEN - 1)
#define N_MAT    8
#define N_MATP   8
#define N_PROCP  5
#define RGAS     8.314f

#define TPB      256
#define EPT      16                   // elements per lane (4 runs x 4)
#define WCHUNK   (64 * EPT)           // 1024 elements per wave
#define WPR      (SEG_LEN / WCHUNK)   // 128 wave-slots per row
#define NWAVE    (N_DATA * WPR)       // 16384 waves total
#define NBLK     (NWAVE / (TPB / 64)) // 4096 blocks (4 independent waves each)

typedef float nt4 __attribute__((ext_vector_type(4)));  // native vec for nontemporal builtin

// sigma_ss = (base_num*u*Lg + Sigma0*cbd) / (Lg*(u+cbd)),  u = R*Lg + 1e-9
__device__ __forceinline__ float stress_s(float t,
    float alpha1, float L0, float G200, float Sigma0, float A0,
    float inv_tau, float cbd, float base_num, float R) {
  float Lg  = G200 * __expf(alpha1 * __logf(t * (1.0f / 200.0f) + 0.001f)) + L0;
  float u   = R * Lg + 1e-9f;
  float num = base_num * u * Lg + Sigma0 * cbd;
  float den = Lg * (u + cbd);
  float sigma_ss = num * __builtin_amdgcn_rcpf(den);
  return sigma_ss + A0 * __expf(-t * inv_tau);
}

// K0: re-arm the packed {ready|value} words (workspace is re-poisoned between
// iterations; poison bits could fake "ready"). Kernel => graph-capture-safe.
__global__ __launch_bounds__(TPB) void k0_init(unsigned long long* __restrict__ cs) {
  cs[blockIdx.x * TPB + threadIdx.x] = 0ull;
}

// Single-pass scan, WAVE-grained, zero barriers, zero LDS, DENSE memory ops.
// Wave w owns elements [w*1024, w*1024+1024). Lane i owns 4 runs of 4
// elements at wavebase + r*256 + i*4 (r=0..3) so every dwordx4 load/store
// has lane i at base+i*16 -> full 1024B per instruction, zero partial-line
// write amplification (round-2's 64B-strided stores cost +53MB HBM writes).
// CORRECTNESS NOTE (round-3 bug): all cross-lane ops (__shfl*) execute in
// FULL exec before any lane-dependent select. Putting a shuffle inside a
// divergent ternary lets the compiler branch it; ds_bpermute from a lane
// inactive in that branch is undefined -> garbage edge values (absmax 2117).
__global__ __launch_bounds__(TPB) void k_scan(
    const float* __restrict__ x,
    const float* __restrict__ pc, const float* __restrict__ raw,
    const float* __restrict__ lb, const float* __restrict__ ub,
    const float* __restrict__ sc, const int* __restrict__ mat_idx,
    unsigned long long* __restrict__ cs,
    float* __restrict__ out) {
  int tid  = threadIdx.x;
  int lane = tid & 63;
  int w    = blockIdx.x * (TPB >> 6) + (tid >> 6);     // global wave id
  int row  = __builtin_amdgcn_readfirstlane(w >> 7);   // wave-uniform -> SGPR
  int s    = __builtin_amdgcn_readfirstlane(w & (WPR - 1));

  // issue x loads immediately (fly during param compute); lane-contiguous
  long rowbase = (long)row * SEG_LEN;
  int  gb0 = s * WCHUNK;                               // row-local wave base
  const float* xp = x + rowbase + gb0 + lane * 4;
  float4 v0 = *(const float4*)(xp);
  float4 v1 = *(const float4*)(xp + 256);
  float4 v2 = *(const float4*)(xp + 512);
  float4 v3 = *(const float4*)(xp + 768);
  float  xe = 0.0f;                                    // cross-wave edge (lane 63, run 3)
  if (lane == 63 && gb0 + WCHUNK < SEG_LEN) xe = x[rowbase + gb0 + WCHUNK];

  // param transform: lanes 0..12 compute one sigmoid each; broadcast by shfl
  float pvl = 0.0f;
  if (lane < 13) {
    int idx = (lane < 5) ? (N_MAT * N_MATP + row * N_PROCP + lane)
                         : (mat_idx[row] * N_MATP + (lane - 5));
    float sg = 1.0f / (1.0f + __expf(-raw[idx]));
    pvl = sg * (ub[idx] - lb[idx]) + lb[idx];
  }
  float SigmaC = __shfl(pvl, 0),  K0   = __shfl(pvl, 1), alpha1 = __shfl(pvl, 2);
  float L0     = __shfl(pvl, 3),  G200 = __shfl(pvl, 4);
  float Sigma0 = __shfl(pvl, 5),  BetaD = __shfl(pvl, 6), Ea = __shfl(pvl, 7);
  float Mfda   = __shfl(pvl, 8),  Di   = __shfl(pvl, 9);
  float A0     = __shfl(pvl, 10), B0   = __shfl(pvl, 11), l0 = __shfl(pvl, 12);

  float R = pc[row * 4 + 0], T = pc[row * 4 + 1], P = pc[row * 4 + 2];
  float cbd      = BetaD * Di * __expf(-Ea / (RGAS * T));
  float base_num = SigmaC - Mfda * P;
  float inv_tau  = 1.0f / (B0 * l0 + 1e-9f);
  float x_min = sc[0], x_sc = sc[1] - sc[0];
  float y_min = sc[2], inv_yr = 1.0f / (sc[3] - sc[2]);

  // x -> t
  float t0[4] = {v0.x*x_sc+x_min, v0.y*x_sc+x_min, v0.z*x_sc+x_min, v0.w*x_sc+x_min};
  float t1[4] = {v1.x*x_sc+x_min, v1.y*x_sc+x_min, v1.z*x_sc+x_min, v1.w*x_sc+x_min};
  float t2[4] = {v2.x*x_sc+x_min, v2.y*x_sc+x_min, v2.z*x_sc+x_min, v2.w*x_sc+x_min};
  float t3[4] = {v3.x*x_sc+x_min, v3.y*x_sc+x_min, v3.z*x_sc+x_min, v3.w*x_sc+x_min};

  // t_next for each run's last element. ALL shuffles in full exec first,
  // then uniform selects (v_cndmask) -- see correctness note above.
  float d0 = __shfl_down(t0[0], 1);   // lane i <- lane i+1, same run
  float d1 = __shfl_down(t1[0], 1);
  float d2 = __shfl_down(t2[0], 1);
  float d3 = __shfl_down(t3[0], 1);
  float b1 = __shfl(t1[0], 0);        // lane 0's first elem of next run
  float b2 = __shfl(t2[0], 0);
  float b3 = __shfl(t3[0], 0);
  float xet = xe * x_sc + x_min;      // cross-wave edge (valid on lane 63)
  bool last = (lane == 63);
  float n0 = last ? b1  : d0;
  float n1 = last ? b2  : d1;
  float n2 = last ? b3  : d2;
  float n3 = last ? xet : d3;

  // products (guard only fails for the global last element of each row)
  int glb = gb0 + lane * 4;   // row-local index of run-0 element 0
  float p0[4], p1[4], p2[4], p3[4];
#define PROD(pd, td, nd, roff)                                              \
  {                                                                         \
    _Pragma("unroll")                                                       \
    for (int k = 0; k < 4; k++) {                                           \
      float tn = (k < 3) ? td[k + 1] : nd;                                  \
      float pp = 0.0f;                                                      \
      if (glb + (roff) + k < NPROD) {                                       \
        float ss = stress_s(td[k], alpha1, L0, G200, Sigma0, A0,            \
                            inv_tau, cbd, base_num, R);                     \
        pp = ss * (tn - td[k]);                                             \
      }                                                                     \
      pd[k] = pp;                                                           \
    }                                                                       \
  }
  PROD(p0, t0, n0, 0)
  PROD(p1, t1, n1, 256)
  PROD(p2, t2, n2, 512)
  PROD(p3, t3, n3, 768)
#undef PROD

  float rs0 = p0[0]+p0[1]+p0[2]+p0[3];
  float rs1 = p1[0]+p1[1]+p1[2]+p1[3];
  float rs2 = p2[0]+p2[1]+p2[2]+p2[3];
  float rs3 = p3[0]+p3[1]+p3[2]+p3[3];

  // wave total via butterfly -> publish ASAP (before scan work)
  float tot = rs0 + rs1 + rs2 + rs3;
#pragma unroll
  for (int d = 1; d < 64; d <<= 1) tot += __shfl_xor(tot, d);
  if (lane == 0) {
    unsigned long long u = (1ull << 32) |
        (unsigned long long)__float_as_uint(tot);
    __hip_atomic_store(cs + w, u, __ATOMIC_RELAXED, __HIP_MEMORY_SCOPE_AGENT);
  }

  // 4 chained inclusive wave-scans -> per-run exclusive prefix (run-major
  // layout: run r spans [r*256, r*256+256), lane i holds [i*4, i*4+4)).
  // This VALU work overlaps predecessors' publishes.
  float carry = 0.0f, e0, e1, e2, e3;
#define SCAN(rs, er)                                                        \
  {                                                                         \
    float inc = rs;                                                         \
    _Pragma("unroll")                                                       \
    for (int d = 1; d < 64; d <<= 1) {                                      \
      float nn = __shfl_up(inc, d);                                         \
      if (lane >= d) inc += nn;                                             \
    }                                                                       \
    er = carry + inc - rs;                                                  \
    carry += __shfl(inc, 63);                                               \
  }
  SCAN(rs0, e0) SCAN(rs1, e1) SCAN(rs2, e2) SCAN(rs3, e3)
#undef SCAN

  // pre-scale store values (row offset folded in after the poll)
  nt4 o0, o1, o2, o3;
#define PREP(od, er, pd)                                                    \
  {                                                                         \
    float c0 = K0 + (er)        - y_min;                                    \
    float c1 = c0 + pd[0];                                                  \
    float c2 = c1 + pd[1];                                                  \
    float c3 = c2 + pd[2];                                                  \
    od.x = c0 * inv_yr; od.y = c1 * inv_yr;                                 \
    od.z = c2 * inv_yr; od.w = c3 * inv_yr;                                 \
  }
  PREP(o0, e0, p0) PREP(o1, e1, p1) PREP(o2, e2, p2) PREP(o3, e3, p3)
#undef PREP

  // poll same-row predecessor slots (lane-strided, <=2 words per lane;
  // predecessors have lower blockIdx => in-order dispatch, earlier waves
  // are co-resident or already done -- rocPRIM single-pass-scan assumption)
  float vsum = 0.0f;
  for (int c = lane; c < s; c += 64) {
    const unsigned long long* p = cs + ((row << 7) + c);
    unsigned long long u = __hip_atomic_load(p, __ATOMIC_RELAXED, __HIP_MEMORY_SCOPE_AGENT);
    while (!(unsigned)(u >> 32)) {
      __builtin_amdgcn_s_sleep(1);
      u = __hip_atomic_load(p, __ATOMIC_RELAXED, __HIP_MEMORY_SCOPE_AGENT);
    }
    vsum += __uint_as_float((unsigned)u);
  }
#pragma unroll
  for (int d = 32; d > 0; d >>= 1) vsum += __shfl_down(vsum, d);
  float choff = __shfl(vsum, 0) * inv_yr;   // already output-scaled

  o0.x += choff; o0.y += choff; o0.z += choff; o0.w += choff;
  o1.x += choff; o1.y += choff; o1.z += choff; o1.w += choff;
  o2.x += choff; o2.y += choff; o2.z += choff; o2.w += choff;
  o3.x += choff; o3.y += choff; o3.z += choff; o3.w += choff;

  // dense nontemporal stores: lane i at base + i*16B, 1024B per instruction
  float* ob = out + rowbase + gb0 + lane * 4;
  __builtin_nontemporal_store(o0, (nt4*)(ob));        // out never re-read:
  __builtin_nontemporal_store(o1, (nt4*)(ob + 256));  // bypass caches,
  __builtin_nontemporal_store(o2, (nt4*)(ob + 512));  // keep x L2/L3-hot
  __builtin_nontemporal_store(o3, (nt4*)(ob + 768));
}

extern "C" void kernel_launch(void* const* d_in, const int* in_sizes, int n_in,
                              void* d_out, int out_size, void* d_ws, size_t ws_size,
                              hipStream_t stream) {
  const float* x_scaled  = (const float*)d_in[0];
  const float* process_c = (const float*)d_in[1];
  const float* raw       = (const float*)d_in[2];
  const float* lb        = (const float*)d_in[3];
  const float* ub        = (const float*)d_in[4];
  const float* sc        = (const float*)d_in[5];
  // d_in[6] = fit_index (unused by the reference computation)
  const int*   mat_idx   = (const int*)d_in[7];
  float* out = (float*)d_out;
  unsigned long long* cs = (unsigned long long*)d_ws;  // 16384 packed {ready|sum}

  k0_init<<<NWAVE / TPB, TPB, 0, stream>>>(cs);
  k_scan<<<NBLK, TPB, 0, stream>>>(
      x_scaled, process_c, raw, lb, ub, sc, mat_idx, cs, out);
}